// Round 2
// baseline (336.815 us; speedup 1.0000x reference)
//
#include <hip/hip_runtime.h>

// Channel self-attention, B=8 C=512 H=W=64 (N=4096), fp32 in/out.
//
//   G  = x x^T  (symmetric: upper-triangle tiles only)  split-bf16, split-K 8
//   U  = wk G                       split x split, split-K 4
//   S  = wq U^T + rank-1 bias terms split x split, split-K 4
//   attn = softmax_rows(S)
//   M  = attn wv                    single bf16
//   out = M x + (attn bv) 1^T       single bf16, Bt = xh^T
//
// gemm_bt: double-buffered counted-vmcnt pipeline, LDS XOR chunk swizzle
// (conflict-free, verified 0 SQ_LDS_BANK_CONFLICT), XCD slab swizzle for G.
// Split-K now writes PRIVATE fp32 partial tiles (plain streaming stores) and
// the consumer kernels (conv_split_g / conv_split / softmax_rows) reduce
// them -- no device-scope atomicAdd (memory-side RMW was serializing the
// epilogue), and no accumulator zeroing/memset anywhere.

typedef unsigned short u16;
typedef short v8s __attribute__((ext_vector_type(8)));
typedef float v4f __attribute__((ext_vector_type(4)));

#define B_ 8
#define C_ 512
#define N_ 4096

__device__ __forceinline__ u16 f2bf(float f) {
  unsigned int u = __builtin_bit_cast(unsigned int, f);
  u = u + 0x7fffu + ((u >> 16) & 1u);
  return (u16)(u >> 16);
}
__device__ __forceinline__ float bf2f(u16 h) {
  unsigned int u = ((unsigned int)h) << 16;
  return __builtin_bit_cast(float, u);
}
__device__ __forceinline__ void gld_lds16(const u16* g, u16* l) {
  __builtin_amdgcn_global_load_lds((__attribute__((address_space(1))) void*)(g),
                                   (__attribute__((address_space(3))) void*)(l),
                                   16, 0, 0);
}

// ---------------- BT-GEMM workhorse (dbuf pipelined + split-K) ----------------
// D[m][n] = sum_k A[m][k] * Bt[n][k].
// blockIdx.z = b * nsplit + ks; block covers K range [ks*Kc, ks*Kc+Kc).
// TRI: 10 upper-triangle (y<=x) 128-tiles of 512x512 C, XCD slab-swizzled.
// SPLIT: A,B each have hi/lo bf16 halves; 3 MFMA products (hh, hl, lh).
// EPI: 2 = bf16-hi store, 3 = fp32 + rowbias store,
//      4 = private fp32 partial-tile store to Cf (slot = z*ntiles + tile).
template <bool SPLIT, int EPI, bool TRI>
__global__ __launch_bounds__(256) void gemm_bt(
    const u16* __restrict__ Ah, const u16* __restrict__ Al, long long sA_,
    const u16* __restrict__ Bh, const u16* __restrict__ Bl, long long sB_,
    int K, int Kc, int nsplit, int ldc,
    float* __restrict__ Cf, u16* __restrict__ Ch,
    long long sC_, const float* __restrict__ rowbias) {
  constexpr int NB = SPLIT ? 4 : 2;  // buffers per stage: A0,A1,B0,B1 or A0,B0
  // [dbuf][which][128*32] : split = 64 KB (2 blocks/CU), nonsplit = 32 KB
  __shared__ __attribute__((aligned(16))) u16 pool[2 * NB * 128 * 32];

  int b, ks, ty_, tx_, tidx;
  if (TRI) {
    // bijective XCD slab swizzle: 640 blocks = 8 XCDs x 80; XCD i gets the
    // contiguous logical range [i*80, i*80+80) = one batch's 10 tiles x 8 ks.
    int L = (int)blockIdx.z * 10 + (int)blockIdx.x;
    int cpx = (B_ * nsplit * 10) >> 3;  // 80 for nsplit=8
    int Ls = (L & 7) * cpx + (L >> 3);
    int t = Ls % 10, z = Ls / 10;
    b = z / nsplit;
    ks = z % nsplit;
    tidx = t;
    ty_ = (t < 4) ? 0 : (t < 7) ? 1 : (t < 9) ? 2 : 3;
    tx_ = t - ((ty_ == 0) ? 0 : (ty_ == 1) ? 3 : (ty_ == 2) ? 5 : 6);
  } else {
    b = blockIdx.z / nsplit;
    ks = blockIdx.z % nsplit;
    ty_ = blockIdx.y;
    tx_ = blockIdx.x;
    tidx = ty_ * 4 + tx_;
  }
  int tid = threadIdx.x, lane = tid & 63, w = tid >> 6;
  const u16* pAh = Ah + (size_t)b * sA_ + (size_t)ty_ * 128 * K;
  const u16* pBh = Bh + (size_t)b * sB_ + (size_t)tx_ * 128 * K;
  const u16* pAl = SPLIT ? (Al + (size_t)b * sA_ + (size_t)ty_ * 128 * K) : pAh;
  const u16* pBl = SPLIT ? (Bl + (size_t)b * sB_ + (size_t)tx_ * 128 * K) : pBh;
  int wr = (w >> 1) * 64, wc = (w & 1) * 64;
  v4f acc[4][4] = {};

  // staging: 4 lanes per 64B row; source chunk XOR-pre-swizzled so that the
  // (linear-dest) global_load_lds lands LDS[row][s] = global[row][s ^ swz(row)]
  // with swz(row) = (row>>1)&3. Read side picks slot q ^ ((r>>1)&3) -> the
  // 64 lanes of a fragment read hit 64 distinct 16B slots: conflict-free.
  int srow_off = lane >> 2;
  int gcol = ((lane & 3) ^ ((lane >> 3) & 3)) * 8;

  const u16* sbase;
  int bufsel;
  if (SPLIT) {
    sbase = (w == 0) ? pAh : (w == 1) ? pAl : (w == 2) ? pBh : pBl;
    bufsel = w;
  } else {
    sbase = (w < 2) ? pAh : pBh;
    bufsel = (w >> 1);
  }

  int kbeg = ks * Kc;
  int nIter = Kc >> 5;

  auto STAGE = [&](int pb, int k0) {
    u16* lds = pool + (pb * NB + bufsel) * (128 * 32);
    if constexpr (SPLIT) {
      for (int t = 0; t < 8; ++t)
        gld_lds16(sbase + (size_t)(t * 16 + srow_off) * K + k0 + gcol,
                  lds + t * 16 * 32);
    } else {
      int o = (w & 1) * 4;
      for (int t = 0; t < 4; ++t) {
        int s = o + t;
        gld_lds16(sbase + (size_t)(s * 16 + srow_off) * K + k0 + gcol,
                  lds + s * 16 * 32);
      }
    }
  };

  int r = lane & 15, q = lane >> 4;
  int sw = (q ^ ((r >> 1) & 3)) * 8;  // swizzled read slot (shorts)

  STAGE(0, kbeg);
  for (int it = 0; it < nIter; ++it) {
    int cur = it & 1;
    bool pf = (it + 1 < nIter);
    if (pf) {
      STAGE(cur ^ 1, kbeg + (it + 1) * 32);
      // counted wait: just-issued 8 (or 4) may stay in flight; drains the
      // previous step's loads (the buffer we're about to read).
      if constexpr (SPLIT)
        asm volatile("s_waitcnt vmcnt(8)" ::: "memory");
      else
        asm volatile("s_waitcnt vmcnt(4)" ::: "memory");
    } else {
      asm volatile("s_waitcnt vmcnt(0)" ::: "memory");
    }
    __builtin_amdgcn_s_barrier();
    __builtin_amdgcn_sched_barrier(0);

    const u16* base = pool + cur * NB * (128 * 32);
    const u16* A0s = base;
    const u16* A1s = base + 128 * 32;
    const u16* B0s = base + (SPLIT ? 2 : 1) * (128 * 32);
    const u16* B1s = base + 3 * (128 * 32);
    v8s a0[4], a1[4], b0[4], b1[4];
    for (int mt = 0; mt < 4; ++mt) {
      int off = (wr + mt * 16 + r) * 32 + sw;
      a0[mt] = *(const v8s*)(const void*)(A0s + off);
      if (SPLIT) a1[mt] = *(const v8s*)(const void*)(A1s + off);
    }
    for (int nt = 0; nt < 4; ++nt) {
      int off = (wc + nt * 16 + r) * 32 + sw;
      b0[nt] = *(const v8s*)(const void*)(B0s + off);
      if (SPLIT) b1[nt] = *(const v8s*)(const void*)(B1s + off);
    }
    for (int mt = 0; mt < 4; ++mt)
      for (int nt = 0; nt < 4; ++nt) {
        acc[mt][nt] = __builtin_amdgcn_mfma_f32_16x16x32_bf16(a0[mt], b0[nt], acc[mt][nt], 0, 0, 0);
        if (SPLIT) {
          acc[mt][nt] = __builtin_amdgcn_mfma_f32_16x16x32_bf16(a0[mt], b1[nt], acc[mt][nt], 0, 0, 0);
          acc[mt][nt] = __builtin_amdgcn_mfma_f32_16x16x32_bf16(a1[mt], b0[nt], acc[mt][nt], 0, 0, 0);
        }
      }
    // WAR fence: all waves must finish reading buf 'cur' before the next
    // iteration's STAGE overwrites it.
    asm volatile("" ::: "memory");
    __builtin_amdgcn_s_barrier();
    asm volatile("" ::: "memory");
  }

  if (EPI == 4) {
    // private partial tile: slot = (b*nsplit+ks)*ntiles + tidx, [128][128] f32
    constexpr int NT = TRI ? 10 : 16;
    float* dstp = Cf + ((size_t)(b * nsplit + ks) * NT + tidx) * 16384;
    for (int mt = 0; mt < 4; ++mt)
      for (int nt = 0; nt < 4; ++nt) {
        int rl = wr + mt * 16 + q * 4;
        int cl = wc + nt * 16 + r;
        for (int e = 0; e < 4; ++e)
          dstp[(size_t)(rl + e) * 128 + cl] = acc[mt][nt][e];
      }
  } else {
    for (int mt = 0; mt < 4; ++mt)
      for (int nt = 0; nt < 4; ++nt) {
        int row0 = ty_ * 128 + wr + mt * 16 + q * 4;
        int col = tx_ * 128 + wc + nt * 16 + r;
        for (int e = 0; e < 4; ++e) {
          float vv = acc[mt][nt][e];
          size_t off = (size_t)b * sC_ + (size_t)(row0 + e) * ldc + col;
          if (EPI == 2) {
            Ch[off] = f2bf(vv);
          } else {
            Cf[off] = vv + rowbias[(size_t)b * C_ + row0 + e];
          }
        }
      }
  }
}

// G partial reduce (8 slots/batch-tile, upper-triangle stored) -> full
// mirrored hi/lo bf16 split buffers. One float4-group per thread.
__global__ __launch_bounds__(256) void conv_split_g(
    const float* __restrict__ P, u16* __restrict__ h, u16* __restrict__ l) {
  size_t i = ((size_t)blockIdx.x * 256 + threadIdx.x) * 4;
  int b = (int)(i >> 18);
  int r = (int)(i >> 9) & 511;
  int c = (int)i & 511;
  int rq = r >> 7, cq = c >> 7;
  float v[4] = {0.f, 0.f, 0.f, 0.f};
  if (rq <= cq) {
    int t = (rq == 0) ? cq : (rq == 1) ? 3 + cq : (rq == 2) ? 5 + cq : 6 + cq;
    const float* p = P + ((size_t)(b * 8) * 10 + t) * 16384 +
                     (size_t)(r & 127) * 128 + (c & 127);
    for (int ks = 0; ks < 8; ++ks) {
      float4 x0 = *(const float4*)(p + (size_t)ks * 10 * 16384);
      v[0] += x0.x; v[1] += x0.y; v[2] += x0.z; v[3] += x0.w;
    }
  } else {
    int t = (cq == 0) ? rq : (cq == 1) ? 3 + rq : (cq == 2) ? 5 + rq : 6 + rq;
    const float* p = P + ((size_t)(b * 8) * 10 + t) * 16384 + (r & 127);
    for (int j = 0; j < 4; ++j)
      for (int ks = 0; ks < 8; ++ks)
        v[j] += p[(size_t)ks * 10 * 16384 + (size_t)((c & 127) + j) * 128];
  }
  for (int j = 0; j < 4; ++j) {
    u16 hh = f2bf(v[j]);
    h[i + j] = hh;
    l[i + j] = f2bf(v[j] - bf2f(hh));
  }
}

// U partial reduce (4 slots) -> hi/lo bf16 split buffers. float4 per thread.
__global__ __launch_bounds__(256) void conv_split(
    const float* __restrict__ P, u16* __restrict__ h, u16* __restrict__ l) {
  size_t i = ((size_t)blockIdx.x * 256 + threadIdx.x) * 4;
  int b = (int)(i >> 18);
  int r = (int)(i >> 9) & 511;
  int c = (int)i & 511;
  int t = (r >> 7) * 4 + (c >> 7);
  const float* p = P + ((size_t)(b * 4) * 16 + t) * 16384 +
                   (size_t)(r & 127) * 128 + (c & 127);
  float v[4] = {0.f, 0.f, 0.f, 0.f};
  for (int ks = 0; ks < 4; ++ks) {
    float4 x0 = *(const float4*)(p + (size_t)ks * 16 * 16384);
    v[0] += x0.x; v[1] += x0.y; v[2] += x0.z; v[3] += x0.w;
  }
  for (int j = 0; j < 4; ++j) {
    u16 hh = f2bf(v[j]);
    h[i + j] = hh;
    l[i + j] = f2bf(v[j] - bf2f(hh));
  }
}

// x (B,C,N) fp32 -> xh/xl bf16 split (same layout), xhT (B,N,C) bf16, sx row
// sums. Vectorized: float4 loads, ushort4 stores, LDS transpose (stride 66,
// <=2-way bank aliasing = free).
__global__ __launch_bounds__(256) void split_transpose(
    const float* __restrict__ x, u16* __restrict__ xh, u16* __restrict__ xl,
    u16* __restrict__ xhT, float* __restrict__ sx) {
  __shared__ u16 tile[64 * 66];  // [n][c] stride 66
  int b = blockIdx.z, ct = blockIdx.y, nt = blockIdx.x;
  int tid = threadIdx.x;
  const float* xb = x + ((size_t)b * C_ + (size_t)ct * 64) * N_ + (size_t)nt * 64;
  for (int it = 0; it < 4; ++it) {
    int idx = it * 1024 + tid * 4;
    int cl = idx >> 6;       // 0..63 local channel
    int nl = idx & 63;       // local n, multiple of 4
    float4 v = *(const float4*)(xb + (size_t)cl * N_ + nl);
    float vv[4] = {v.x, v.y, v.z, v.w};
    u16 h4[4], l4[4];
    for (int j = 0; j < 4; ++j) {
      h4[j] = f2bf(vv[j]);
      l4[j] = f2bf(vv[j] - bf2f(h4[j]));
    }
    size_t go = ((size_t)b * C_ + ct * 64 + cl) * N_ + (size_t)nt * 64 + nl;
    *(ushort4*)(xh + go) = make_ushort4(h4[0], h4[1], h4[2], h4[3]);
    *(ushort4*)(xl + go) = make_ushort4(l4[0], l4[1], l4[2], l4[3]);
    for (int j = 0; j < 4; ++j) tile[(nl + j) * 66 + cl] = h4[j];
    float s = vv[0] + vv[1] + vv[2] + vv[3];
    s += __shfl_xor(s, 1); s += __shfl_xor(s, 2);
    s += __shfl_xor(s, 4); s += __shfl_xor(s, 8);
    if ((tid & 15) == 0) atomicAdd(&sx[b * C_ + ct * 64 + cl], s);
  }
  __syncthreads();
  for (int it = 0; it < 4; ++it) {
    int idx = it * 1024 + tid * 4;
    int nr = idx >> 6;       // local n row
    int c4 = idx & 63;       // local c, multiple of 4
    const u16* tp = tile + nr * 66 + c4;
    unsigned int lo = *(const unsigned int*)(const void*)(tp);
    unsigned int hi = *(const unsigned int*)(const void*)(tp + 2);
    size_t to = ((size_t)b * N_ + (size_t)nt * 64 + nr) * C_ + ct * 64 + c4;
    *(ushort4*)(xhT + to) = make_ushort4((u16)lo, (u16)(lo >> 16), (u16)hi, (u16)(hi >> 16));
  }
}

// wq,wk -> bf16 hi/lo splits; wv -> wvT bf16 (transposed). Block 0..15 zero SX.
__global__ __launch_bounds__(256) void prep_weights(
    const float* __restrict__ wq, const float* __restrict__ wk, const float* __restrict__ wv,
    u16* __restrict__ wqh, u16* __restrict__ wql, u16* __restrict__ wkh,
    u16* __restrict__ wkl, u16* __restrict__ wvT, float* __restrict__ sx) {
  int idx = blockIdx.x * 256 + threadIdx.x;
  if (blockIdx.x < 16) sx[idx] = 0.0f;
  float q = wq[idx];
  u16 qh = f2bf(q);
  wqh[idx] = qh;
  wql[idx] = f2bf(q - bf2f(qh));
  float k = wk[idx];
  u16 kh = f2bf(k);
  wkh[idx] = kh;
  wkl[idx] = f2bf(k - bf2f(kh));
  float v = wv[idx];
  wvT[(size_t)(idx & 511) * C_ + (idx >> 9)] = f2bf(v);
}

// aq[b,i] = sum_c wq[i,c] sx[b,c];  ak[b,j] = sum_c wk[j,c] sx[b,c]
__global__ __launch_bounds__(256) void bias_vec(
    const float* __restrict__ wq, const float* __restrict__ wk,
    const float* __restrict__ sx, float* __restrict__ aq, float* __restrict__ ak) {
  int gw = blockIdx.x * 4 + (threadIdx.x >> 6);  // 0..8191
  int lane = threadIdx.x & 63;
  int which = gw >> 12;
  int b = (gw >> 9) & 7, i = gw & 511;
  const float* wrow = (which ? wk : wq) + (size_t)i * C_;
  const float* sxb = sx + b * C_;
  float s = 0.f;
  for (int c = lane; c < C_; c += 64) s += wrow[c] * sxb[c];
  for (int o = 32; o; o >>= 1) s += __shfl_down(s, o);
  if (lane == 0) (which ? ak : aq)[b * C_ + i] = s;
}

// one wave per row: reduce 4 S-partials, add bias terms, softmax,
// emit attn bf16 + obias = attn.bv
__global__ __launch_bounds__(256) void softmax_rows(
    const float* __restrict__ P, const float* __restrict__ aq,
    const float* __restrict__ ak, const float* __restrict__ bq,
    const float* __restrict__ bk, const float* __restrict__ bv,
    u16* __restrict__ attn, float* __restrict__ obias) {
  int row = blockIdx.x * 4 + (threadIdx.x >> 6);  // b*512 + i
  int lane = threadIdx.x & 63;
  int b = row >> 9, i = row & 511;
  const float* akb = ak + b * C_;
  float aqi = aq[row], bqi = bq[i];
  float lv[8], ev[8];
  float m = -3.4e38f;
  for (int t = 0; t < 8; ++t) {
    int j = t * 64 + lane;
    int tile = (i >> 7) * 4 + (t >> 1);
    size_t base = ((size_t)(b * 4) * 16 + tile) * 16384 +
                  (size_t)(i & 127) * 128 + ((t & 1) * 64 + lane);
    float sv = 0.f;
    for (int ks = 0; ks < 4; ++ks) sv += P[base + (size_t)ks * 16 * 16384];
    float v = sv + aqi * bk[j] + bqi * (akb[j] + 4096.0f * bk[j]);
    lv[t] = v;
    m = fmaxf(m, v);
  }
  for (int o = 32; o; o >>= 1) m = fmaxf(m, __shfl_xor(m, o));
  float se = 0.f, sb = 0.f;
  for (int t = 0; t < 8; ++t) {
    int j = t * 64 + lane;
    float e = expf(lv[t] - m);
    ev[t] = e;
    se += e;
    sb += e * bv[j];
  }
  for (int o = 32; o; o >>= 1) {
    se += __shfl_xor(se, o);
    sb += __shfl_xor(sb, o);
  }
  float inv = 1.0f / se;
  for (int t = 0; t < 8; ++t) attn[(size_t)row * C_ + t * 64 + lane] = f2bf(ev[t] * inv);
  if (lane == 0) obias[row] = sb * inv;
}

extern "C" void kernel_launch(void* const* d_in, const int* in_sizes, int n_in,
                              void* d_out, int out_size, void* d_ws, size_t ws_size,
                              hipStream_t stream) {
  const float* x = (const float*)d_in[0];
  const float* wq = (const float*)d_in[1];
  const float* bq = (const float*)d_in[2];
  const float* wk = (const float*)d_in[3];
  const float* bk = (const float*)d_in[4];
  const float* wv = (const float*)d_in[5];
  const float* bv = (const float*)d_in[6];
  float* out = (float*)d_out;

  const size_t XN = (size_t)B_ * C_ * N_;   // 16.78M elems
  const size_t CCt = (size_t)B_ * C_ * C_;  // 2.10M elems
  const size_t W2 = (size_t)C_ * C_;
  const size_t PARTN = (size_t)B_ * 8 * 10 * 16384;  // 10.49M floats (41.9 MB)

  u16* XH = (u16*)d_ws;
  u16* XL = XH + XN;
  u16* XHT = XL + XN;
  float* PART = (float*)(XHT + XN);         // split-K partials (G:80, U/S:64 slots/b)
  u16* GH = (u16*)(PART + PARTN);
  u16* GL = GH + CCt;
  u16* UH = GL + CCt;
  u16* UL = UH + CCt;
  u16* ATTN = UL + CCt;
  u16* MH = ATTN + CCt;
  u16* WQH = MH + CCt;
  u16* WQL = WQH + W2;
  u16* WKH = WQL + W2;
  u16* WKL = WKH + W2;
  u16* WVT = WKL + W2;
  float* SX = (float*)(WVT + W2);
  float* AQ = SX + B_ * C_;
  float* AK = AQ + B_ * C_;
  float* OBIAS = AK + B_ * C_;

  prep_weights<<<W2 / 256, 256, 0, stream>>>(wq, wk, wv, WQH, WQL, WKH, WKL, WVT, SX);
  split_transpose<<<dim3(N_ / 64, C_ / 64, B_), 256, 0, stream>>>(x, XH, XL, XHT, SX);
  bias_vec<<<2048, 256, 0, stream>>>(wq, wk, SX, AQ, AK);

  // G = x x^T  -- upper-triangle tiles, split-K 8, private partial stores
  gemm_bt<true, 4, true><<<dim3(10, 1, B_ * 8), 256, 0, stream>>>(
      XH, XL, (long long)((size_t)C_ * N_), XH, XL, (long long)((size_t)C_ * N_),
      N_, 512, 8, C_, PART, nullptr, (long long)W2, nullptr);
  conv_split_g<<<CCt / 1024, 256, 0, stream>>>(PART, GH, GL);

  // U = wk G   -- split-K 4 (A = wk split, Bt = G split; G symmetric)
  gemm_bt<true, 4, false><<<dim3(4, 4, B_ * 4), 256, 0, stream>>>(
      WKH, WKL, 0, GH, GL, (long long)W2, C_, 128, 4, C_, PART, nullptr,
      (long long)W2, nullptr);
  conv_split<<<CCt / 1024, 256, 0, stream>>>(PART, UH, UL);

  // S = wq U^T -- split-K 4, private partial stores
  gemm_bt<true, 4, false><<<dim3(4, 4, B_ * 4), 256, 0, stream>>>(
      WQH, WQL, 0, UH, UL, (long long)W2, C_, 128, 4, C_, PART, nullptr,
      (long long)W2, nullptr);

  softmax_rows<<<(B_ * C_) / 4, 256, 0, stream>>>(PART, AQ, AK, bq, bk, bv, ATTN, OBIAS);

  // M = attn wv  (Bt = wv^T), bf16-hi store
  gemm_bt<false, 2, false><<<dim3(4, 4, B_), 256, 0, stream>>>(
      ATTN, nullptr, (long long)W2, WVT, nullptr, 0, C_, 512, 1, C_, nullptr,
      MH, (long long)W2, nullptr);
  // out = M x + obias  (Bt = xh^T)
  gemm_bt<false, 3, false><<<dim3(N_ / 128, 4, B_), 256, 0, stream>>>(
      MH, nullptr, (long long)W2, XHT, nullptr, (long long)((size_t)N_ * C_),
      C_, 512, 1, N_, out, nullptr, (long long)((size_t)C_ * N_), OBIAS);
}

// Round 3
// 278.620 us; speedup vs baseline: 1.2089x; 1.2089x over previous
//
#include <hip/hip_runtime.h>

// Channel self-attention, B=8 C=512 H=W=64 (N=4096), fp32 in/out.
//
//   G  = x x^T  (symmetric: upper-triangle tiles only)  split-bf16, split-K 8
//   U  = wk G                       split x split, split-K 4
//   S  = wq U^T + rank-1 bias terms split x split, split-K 4
//   attn = softmax_rows(S)
//   M  = attn wv                    single bf16
//   out = M x + (attn bv) 1^T       single bf16, Bt = xh^T
//
// gemm_bt: double-buffered counted-vmcnt pipeline, LDS XOR chunk swizzle
// (conflict-free, verified 0 SQ_LDS_BANK_CONFLICT), XCD slab swizzle for G.
// Split-K writes PRIVATE fp32 partial tiles (streaming stores); consumers
// reduce them. conv_split_g reduces with fully-coalesced row-major reads and
// produces the mirrored lower-triangle copy via a padded LDS transpose
// (round-2 version read the mirror column-major: 126 MB FETCH, 70 us).

typedef unsigned short u16;
typedef short v8s __attribute__((ext_vector_type(8)));
typedef float v4f __attribute__((ext_vector_type(4)));

#define B_ 8
#define C_ 512
#define N_ 4096

__device__ __forceinline__ u16 f2bf(float f) {
  unsigned int u = __builtin_bit_cast(unsigned int, f);
  u = u + 0x7fffu + ((u >> 16) & 1u);
  return (u16)(u >> 16);
}
__device__ __forceinline__ float bf2f(u16 h) {
  unsigned int u = ((unsigned int)h) << 16;
  return __builtin_bit_cast(float, u);
}
__device__ __forceinline__ void gld_lds16(const u16* g, u16* l) {
  __builtin_amdgcn_global_load_lds((__attribute__((address_space(1))) void*)(g),
                                   (__attribute__((address_space(3))) void*)(l),
                                   16, 0, 0);
}

// ---------------- BT-GEMM workhorse (dbuf pipelined + split-K) ----------------
// D[m][n] = sum_k A[m][k] * Bt[n][k].
// blockIdx.z = b * nsplit + ks; block covers K range [ks*Kc, ks*Kc+Kc).
// TRI: 10 upper-triangle (y<=x) 128-tiles of 512x512 C, XCD slab-swizzled.
// SPLIT: A,B each have hi/lo bf16 halves; 3 MFMA products (hh, hl, lh).
// EPI: 2 = bf16-hi store, 3 = fp32 + rowbias store,
//      4 = private fp32 partial-tile store to Cf (slot = z*ntiles + tile).
template <bool SPLIT, int EPI, bool TRI>
__global__ __launch_bounds__(256) void gemm_bt(
    const u16* __restrict__ Ah, const u16* __restrict__ Al, long long sA_,
    const u16* __restrict__ Bh, const u16* __restrict__ Bl, long long sB_,
    int K, int Kc, int nsplit, int ldc,
    float* __restrict__ Cf, u16* __restrict__ Ch,
    long long sC_, const float* __restrict__ rowbias) {
  constexpr int NB = SPLIT ? 4 : 2;  // buffers per stage: A0,A1,B0,B1 or A0,B0
  // [dbuf][which][128*32] : split = 64 KB (2 blocks/CU), nonsplit = 32 KB
  __shared__ __attribute__((aligned(16))) u16 pool[2 * NB * 128 * 32];

  int b, ks, ty_, tx_, tidx;
  if (TRI) {
    // bijective XCD slab swizzle: 640 blocks = 8 XCDs x 80; XCD i gets the
    // contiguous logical range [i*80, i*80+80) = one batch's 10 tiles x 8 ks.
    int L = (int)blockIdx.z * 10 + (int)blockIdx.x;
    int cpx = (B_ * nsplit * 10) >> 3;  // 80 for nsplit=8
    int Ls = (L & 7) * cpx + (L >> 3);
    int t = Ls % 10, z = Ls / 10;
    b = z / nsplit;
    ks = z % nsplit;
    tidx = t;
    ty_ = (t < 4) ? 0 : (t < 7) ? 1 : (t < 9) ? 2 : 3;
    tx_ = t - ((ty_ == 0) ? 0 : (ty_ == 1) ? 3 : (ty_ == 2) ? 5 : 6);
  } else {
    b = blockIdx.z / nsplit;
    ks = blockIdx.z % nsplit;
    ty_ = blockIdx.y;
    tx_ = blockIdx.x;
    tidx = ty_ * 4 + tx_;
  }
  int tid = threadIdx.x, lane = tid & 63, w = tid >> 6;
  const u16* pAh = Ah + (size_t)b * sA_ + (size_t)ty_ * 128 * K;
  const u16* pBh = Bh + (size_t)b * sB_ + (size_t)tx_ * 128 * K;
  const u16* pAl = SPLIT ? (Al + (size_t)b * sA_ + (size_t)ty_ * 128 * K) : pAh;
  const u16* pBl = SPLIT ? (Bl + (size_t)b * sB_ + (size_t)tx_ * 128 * K) : pBh;
  int wr = (w >> 1) * 64, wc = (w & 1) * 64;
  v4f acc[4][4] = {};

  // staging: 4 lanes per 64B row; source chunk XOR-pre-swizzled so that the
  // (linear-dest) global_load_lds lands LDS[row][s] = global[row][s ^ swz(row)]
  // with swz(row) = (row>>1)&3. Read side picks slot q ^ ((r>>1)&3) -> the
  // 64 lanes of a fragment read hit 64 distinct 16B slots: conflict-free.
  int srow_off = lane >> 2;
  int gcol = ((lane & 3) ^ ((lane >> 3) & 3)) * 8;

  const u16* sbase;
  int bufsel;
  if (SPLIT) {
    sbase = (w == 0) ? pAh : (w == 1) ? pAl : (w == 2) ? pBh : pBl;
    bufsel = w;
  } else {
    sbase = (w < 2) ? pAh : pBh;
    bufsel = (w >> 1);
  }

  int kbeg = ks * Kc;
  int nIter = Kc >> 5;

  auto STAGE = [&](int pb, int k0) {
    u16* lds = pool + (pb * NB + bufsel) * (128 * 32);
    if constexpr (SPLIT) {
      for (int t = 0; t < 8; ++t)
        gld_lds16(sbase + (size_t)(t * 16 + srow_off) * K + k0 + gcol,
                  lds + t * 16 * 32);
    } else {
      int o = (w & 1) * 4;
      for (int t = 0; t < 4; ++t) {
        int s = o + t;
        gld_lds16(sbase + (size_t)(s * 16 + srow_off) * K + k0 + gcol,
                  lds + s * 16 * 32);
      }
    }
  };

  int r = lane & 15, q = lane >> 4;
  int sw = (q ^ ((r >> 1) & 3)) * 8;  // swizzled read slot (shorts)

  STAGE(0, kbeg);
  for (int it = 0; it < nIter; ++it) {
    int cur = it & 1;
    bool pf = (it + 1 < nIter);
    if (pf) {
      STAGE(cur ^ 1, kbeg + (it + 1) * 32);
      // counted wait: just-issued 8 (or 4) may stay in flight; drains the
      // previous step's loads (the buffer we're about to read).
      if constexpr (SPLIT)
        asm volatile("s_waitcnt vmcnt(8)" ::: "memory");
      else
        asm volatile("s_waitcnt vmcnt(4)" ::: "memory");
    } else {
      asm volatile("s_waitcnt vmcnt(0)" ::: "memory");
    }
    __builtin_amdgcn_s_barrier();
    __builtin_amdgcn_sched_barrier(0);

    const u16* base = pool + cur * NB * (128 * 32);
    const u16* A0s = base;
    const u16* A1s = base + 128 * 32;
    const u16* B0s = base + (SPLIT ? 2 : 1) * (128 * 32);
    const u16* B1s = base + 3 * (128 * 32);
    v8s a0[4], a1[4], b0[4], b1[4];
    for (int mt = 0; mt < 4; ++mt) {
      int off = (wr + mt * 16 + r) * 32 + sw;
      a0[mt] = *(const v8s*)(const void*)(A0s + off);
      if (SPLIT) a1[mt] = *(const v8s*)(const void*)(A1s + off);
    }
    for (int nt = 0; nt < 4; ++nt) {
      int off = (wc + nt * 16 + r) * 32 + sw;
      b0[nt] = *(const v8s*)(const void*)(B0s + off);
      if (SPLIT) b1[nt] = *(const v8s*)(const void*)(B1s + off);
    }
    for (int mt = 0; mt < 4; ++mt)
      for (int nt = 0; nt < 4; ++nt) {
        acc[mt][nt] = __builtin_amdgcn_mfma_f32_16x16x32_bf16(a0[mt], b0[nt], acc[mt][nt], 0, 0, 0);
        if (SPLIT) {
          acc[mt][nt] = __builtin_amdgcn_mfma_f32_16x16x32_bf16(a0[mt], b1[nt], acc[mt][nt], 0, 0, 0);
          acc[mt][nt] = __builtin_amdgcn_mfma_f32_16x16x32_bf16(a1[mt], b0[nt], acc[mt][nt], 0, 0, 0);
        }
      }
    // WAR fence: all waves must finish reading buf 'cur' before the next
    // iteration's STAGE overwrites it.
    asm volatile("" ::: "memory");
    __builtin_amdgcn_s_barrier();
    asm volatile("" ::: "memory");
  }

  if (EPI == 4) {
    // private partial tile: slot = (b*nsplit+ks)*ntiles + tidx, [128][128] f32
    constexpr int NT = TRI ? 10 : 16;
    float* dstp = Cf + ((size_t)(b * nsplit + ks) * NT + tidx) * 16384;
    for (int mt = 0; mt < 4; ++mt)
      for (int nt = 0; nt < 4; ++nt) {
        int rl = wr + mt * 16 + q * 4;
        int cl = wc + nt * 16 + r;
        for (int e = 0; e < 4; ++e)
          dstp[(size_t)(rl + e) * 128 + cl] = acc[mt][nt][e];
      }
  } else {
    for (int mt = 0; mt < 4; ++mt)
      for (int nt = 0; nt < 4; ++nt) {
        int row0 = ty_ * 128 + wr + mt * 16 + q * 4;
        int col = tx_ * 128 + wc + nt * 16 + r;
        for (int e = 0; e < 4; ++e) {
          float vv = acc[mt][nt][e];
          size_t off = (size_t)b * sC_ + (size_t)(row0 + e) * ldc + col;
          if (EPI == 2) {
            Ch[off] = f2bf(vv);
          } else {
            Cf[off] = vv + rowbias[(size_t)b * C_ + row0 + e];
          }
        }
      }
  }
}

// G partial reduce: 160 blocks = (b:8) x (tri tile t:10) x (row half:2).
// b = blockIdx.x & 7 so consecutive blocks -> consecutive XCDs (partials for
// batch b were produced on XCD b). Pass 1: reduce 8 ks slots with coalesced
// float4 row-major reads, write hi/lo at (rq,cq), stage into padded LDS.
// Pass 2 (off-diag only): LDS-transposed read (stride 133: 16-bank, 2-way =
// free), coalesced ushort4 write of the mirrored (cq,rq) tile.
__global__ __launch_bounds__(256) void conv_split_g(
    const float* __restrict__ P, u16* __restrict__ h, u16* __restrict__ l) {
  __shared__ u16 th[64 * 133];
  __shared__ u16 tl[64 * 133];
  int j = blockIdx.x;
  int b = j & 7;
  int rest = j >> 3;         // 0..19
  int t = rest >> 1;         // tri tile 0..9
  int half = rest & 1;       // which 64-row half
  int rq = (t < 4) ? 0 : (t < 7) ? 1 : (t < 9) ? 2 : 3;
  int cq = t - ((rq == 0) ? 0 : (rq == 1) ? 3 : (rq == 2) ? 5 : 6);
  const float* p0 = P + ((size_t)(b * 8) * 10 + t) * 16384 + (size_t)(half * 64) * 128;
  int tid = threadIdx.x;
  int lr = tid >> 5;         // 0..7
  int c4 = (tid & 31) * 4;   // 0..124
  for (int it = 0; it < 8; ++it) {
    int row = it * 8 + lr;   // 0..63 within half
    const float* pr = p0 + (size_t)row * 128 + c4;
    float v[4] = {0.f, 0.f, 0.f, 0.f};
    for (int ks = 0; ks < 8; ++ks) {
      float4 x = *(const float4*)(pr + (size_t)ks * 10 * 16384);
      v[0] += x.x; v[1] += x.y; v[2] += x.z; v[3] += x.w;
    }
    u16 h4[4], l4[4];
    for (int e = 0; e < 4; ++e) {
      h4[e] = f2bf(v[e]);
      l4[e] = f2bf(v[e] - bf2f(h4[e]));
    }
    int gr = rq * 128 + half * 64 + row, gc = cq * 128 + c4;
    size_t go = ((size_t)b << 18) + (size_t)gr * C_ + gc;
    *(ushort4*)(h + go) = make_ushort4(h4[0], h4[1], h4[2], h4[3]);
    *(ushort4*)(l + go) = make_ushort4(l4[0], l4[1], l4[2], l4[3]);
    for (int e = 0; e < 4; ++e) {
      th[row * 133 + c4 + e] = h4[e];
      tl[row * 133 + c4 + e] = l4[e];
    }
  }
  if (rq == cq) return;  // diagonal: no mirror needed
  __syncthreads();
  int orw = tid >> 4;        // output-row step base (0..15)
  int oc4 = (tid & 15) * 4;  // 0..60 (original-row index within half)
  for (int it = 0; it < 8; ++it) {
    int orr = it * 16 + orw;  // 0..127 = original col
    u16 h4[4], l4[4];
    for (int e = 0; e < 4; ++e) {
      h4[e] = th[(oc4 + e) * 133 + orr];
      l4[e] = tl[(oc4 + e) * 133 + orr];
    }
    int gr = cq * 128 + orr, gc = rq * 128 + half * 64 + oc4;
    size_t go = ((size_t)b << 18) + (size_t)gr * C_ + gc;
    *(ushort4*)(h + go) = make_ushort4(h4[0], h4[1], h4[2], h4[3]);
    *(ushort4*)(l + go) = make_ushort4(l4[0], l4[1], l4[2], l4[3]);
  }
}

// U partial reduce (4 slots) -> hi/lo bf16 split buffers. float4 per thread.
__global__ __launch_bounds__(256) void conv_split(
    const float* __restrict__ P, u16* __restrict__ h, u16* __restrict__ l) {
  size_t i = ((size_t)blockIdx.x * 256 + threadIdx.x) * 4;
  int b = (int)(i >> 18);
  int r = (int)(i >> 9) & 511;
  int c = (int)i & 511;
  int t = (r >> 7) * 4 + (c >> 7);
  const float* p = P + ((size_t)(b * 4) * 16 + t) * 16384 +
                   (size_t)(r & 127) * 128 + (c & 127);
  float v[4] = {0.f, 0.f, 0.f, 0.f};
  for (int ks = 0; ks < 4; ++ks) {
    float4 x0 = *(const float4*)(p + (size_t)ks * 16 * 16384);
    v[0] += x0.x; v[1] += x0.y; v[2] += x0.z; v[3] += x0.w;
  }
  for (int j = 0; j < 4; ++j) {
    u16 hh = f2bf(v[j]);
    h[i + j] = hh;
    l[i + j] = f2bf(v[j] - bf2f(hh));
  }
}

// x (B,C,N) fp32 -> xh/xl bf16 split (same layout), xhT (B,N,C) bf16, sx row
// sums. Vectorized: float4 loads, ushort4 stores, LDS transpose (stride 66,
// <=2-way bank aliasing = free).
__global__ __launch_bounds__(256) void split_transpose(
    const float* __restrict__ x, u16* __restrict__ xh, u16* __restrict__ xl,
    u16* __restrict__ xhT, float* __restrict__ sx) {
  __shared__ u16 tile[64 * 66];  // [n][c] stride 66
  int b = blockIdx.z, ct = blockIdx.y, nt = blockIdx.x;
  int tid = threadIdx.x;
  const float* xb = x + ((size_t)b * C_ + (size_t)ct * 64) * N_ + (size_t)nt * 64;
  for (int it = 0; it < 4; ++it) {
    int idx = it * 1024 + tid * 4;
    int cl = idx >> 6;       // 0..63 local channel
    int nl = idx & 63;       // local n, multiple of 4
    float4 v = *(const float4*)(xb + (size_t)cl * N_ + nl);
    float vv[4] = {v.x, v.y, v.z, v.w};
    u16 h4[4], l4[4];
    for (int j = 0; j < 4; ++j) {
      h4[j] = f2bf(vv[j]);
      l4[j] = f2bf(vv[j] - bf2f(h4[j]));
    }
    size_t go = ((size_t)b * C_ + ct * 64 + cl) * N_ + (size_t)nt * 64 + nl;
    *(ushort4*)(xh + go) = make_ushort4(h4[0], h4[1], h4[2], h4[3]);
    *(ushort4*)(xl + go) = make_ushort4(l4[0], l4[1], l4[2], l4[3]);
    for (int j = 0; j < 4; ++j) tile[(nl + j) * 66 + cl] = h4[j];
    float s = vv[0] + vv[1] + vv[2] + vv[3];
    s += __shfl_xor(s, 1); s += __shfl_xor(s, 2);
    s += __shfl_xor(s, 4); s += __shfl_xor(s, 8);
    if ((tid & 15) == 0) atomicAdd(&sx[b * C_ + ct * 64 + cl], s);
  }
  __syncthreads();
  for (int it = 0; it < 4; ++it) {
    int idx = it * 1024 + tid * 4;
    int nr = idx >> 6;       // local n row
    int c4 = idx & 63;       // local c, multiple of 4
    const u16* tp = tile + nr * 66 + c4;
    unsigned int lo = *(const unsigned int*)(const void*)(tp);
    unsigned int hi = *(const unsigned int*)(const void*)(tp + 2);
    size_t to = ((size_t)b * N_ + (size_t)nt * 64 + nr) * C_ + ct * 64 + c4;
    *(ushort4*)(xhT + to) = make_ushort4((u16)lo, (u16)(lo >> 16), (u16)hi, (u16)(hi >> 16));
  }
}

// wq,wk -> bf16 hi/lo splits; wv -> wvT bf16 (transposed). Block 0..15 zero SX.
__global__ __launch_bounds__(256) void prep_weights(
    const float* __restrict__ wq, const float* __restrict__ wk, const float* __restrict__ wv,
    u16* __restrict__ wqh, u16* __restrict__ wql, u16* __restrict__ wkh,
    u16* __restrict__ wkl, u16* __restrict__ wvT, float* __restrict__ sx) {
  int idx = blockIdx.x * 256 + threadIdx.x;
  if (blockIdx.x < 16) sx[idx] = 0.0f;
  float q = wq[idx];
  u16 qh = f2bf(q);
  wqh[idx] = qh;
  wql[idx] = f2bf(q - bf2f(qh));
  float k = wk[idx];
  u16 kh = f2bf(k);
  wkh[idx] = kh;
  wkl[idx] = f2bf(k - bf2f(kh));
  float v = wv[idx];
  wvT[(size_t)(idx & 511) * C_ + (idx >> 9)] = f2bf(v);
}

// aq[b,i] = sum_c wq[i,c] sx[b,c];  ak[b,j] = sum_c wk[j,c] sx[b,c]
__global__ __launch_bounds__(256) void bias_vec(
    const float* __restrict__ wq, const float* __restrict__ wk,
    const float* __restrict__ sx, float* __restrict__ aq, float* __restrict__ ak) {
  int gw = blockIdx.x * 4 + (threadIdx.x >> 6);  // 0..8191
  int lane = threadIdx.x & 63;
  int which = gw >> 12;
  int b = (gw >> 9) & 7, i = gw & 511;
  const float* wrow = (which ? wk : wq) + (size_t)i * C_;
  const float* sxb = sx + b * C_;
  float s = 0.f;
  for (int c = lane; c < C_; c += 64) s += wrow[c] * sxb[c];
  for (int o = 32; o; o >>= 1) s += __shfl_down(s, o);
  if (lane == 0) (which ? ak : aq)[b * C_ + i] = s;
}

// one wave per row: reduce 4 S-partials, add bias terms, softmax,
// emit attn bf16 + obias = attn.bv
__global__ __launch_bounds__(256) void softmax_rows(
    const float* __restrict__ P, const float* __restrict__ aq,
    const float* __restrict__ ak, const float* __restrict__ bq,
    const float* __restrict__ bk, const float* __restrict__ bv,
    u16* __restrict__ attn, float* __restrict__ obias) {
  int row = blockIdx.x * 4 + (threadIdx.x >> 6);  // b*512 + i
  int lane = threadIdx.x & 63;
  int b = row >> 9, i = row & 511;
  const float* akb = ak + b * C_;
  float aqi = aq[row], bqi = bq[i];
  float lv[8], ev[8];
  float m = -3.4e38f;
  for (int t = 0; t < 8; ++t) {
    int j = t * 64 + lane;
    int tile = (i >> 7) * 4 + (t >> 1);
    size_t base = ((size_t)(b * 4) * 16 + tile) * 16384 +
                  (size_t)(i & 127) * 128 + ((t & 1) * 64 + lane);
    float sv = 0.f;
    for (int ks = 0; ks < 4; ++ks) sv += P[base + (size_t)ks * 16 * 16384];
    float v = sv + aqi * bk[j] + bqi * (akb[j] + 4096.0f * bk[j]);
    lv[t] = v;
    m = fmaxf(m, v);
  }
  for (int o = 32; o; o >>= 1) m = fmaxf(m, __shfl_xor(m, o));
  float se = 0.f, sb = 0.f;
  for (int t = 0; t < 8; ++t) {
    int j = t * 64 + lane;
    float e = expf(lv[t] - m);
    ev[t] = e;
    se += e;
    sb += e * bv[j];
  }
  for (int o = 32; o; o >>= 1) {
    se += __shfl_xor(se, o);
    sb += __shfl_xor(sb, o);
  }
  float inv = 1.0f / se;
  for (int t = 0; t < 8; ++t) attn[(size_t)row * C_ + t * 64 + lane] = f2bf(ev[t] * inv);
  if (lane == 0) obias[row] = sb * inv;
}

extern "C" void kernel_launch(void* const* d_in, const int* in_sizes, int n_in,
                              void* d_out, int out_size, void* d_ws, size_t ws_size,
                              hipStream_t stream) {
  const float* x = (const float*)d_in[0];
  const float* wq = (const float*)d_in[1];
  const float* bq = (const float*)d_in[2];
  const float* wk = (const float*)d_in[3];
  const float* bk = (const float*)d_in[4];
  const float* wv = (const float*)d_in[5];
  const float* bv = (const float*)d_in[6];
  float* out = (float*)d_out;

  const size_t XN = (size_t)B_ * C_ * N_;   // 16.78M elems
  const size_t CCt = (size_t)B_ * C_ * C_;  // 2.10M elems
  const size_t W2 = (size_t)C_ * C_;
  const size_t PARTN = (size_t)B_ * 8 * 10 * 16384;  // 10.49M floats (41.9 MB)

  u16* XH = (u16*)d_ws;
  u16* XL = XH + XN;
  u16* XHT = XL + XN;
  float* PART = (float*)(XHT + XN);         // split-K partials (G:80, U/S:64 slots/b)
  u16* GH = (u16*)(PART + PARTN);
  u16* GL = GH + CCt;
  u16* UH = GL + CCt;
  u16* UL = UH + CCt;
  u16* ATTN = UL + CCt;
  u16* MH = ATTN + CCt;
  u16* WQH = MH + CCt;
  u16* WQL = WQH + W2;
  u16* WKH = WQL + W2;
  u16* WKL = WKH + W2;
  u16* WVT = WKL + W2;
  float* SX = (float*)(WVT + W2);
  float* AQ = SX + B_ * C_;
  float* AK = AQ + B_ * C_;
  float* OBIAS = AK + B_ * C_;

  prep_weights<<<W2 / 256, 256, 0, stream>>>(wq, wk, wv, WQH, WQL, WKH, WKL, WVT, SX);
  split_transpose<<<dim3(N_ / 64, C_ / 64, B_), 256, 0, stream>>>(x, XH, XL, XHT, SX);
  bias_vec<<<2048, 256, 0, stream>>>(wq, wk, SX, AQ, AK);

  // G = x x^T  -- upper-triangle tiles, split-K 8, private partial stores
  gemm_bt<true, 4, true><<<dim3(10, 1, B_ * 8), 256, 0, stream>>>(
      XH, XL, (long long)((size_t)C_ * N_), XH, XL, (long long)((size_t)C_ * N_),
      N_, 512, 8, C_, PART, nullptr, (long long)W2, nullptr);
  conv_split_g<<<160, 256, 0, stream>>>(PART, GH, GL);

  // U = wk G   -- split-K 4 (A = wk split, Bt = G split; G symmetric)
  gemm_bt<true, 4, false><<<dim3(4, 4, B_ * 4), 256, 0, stream>>>(
      WKH, WKL, 0, GH, GL, (long long)W2, C_, 128, 4, C_, PART, nullptr,
      (long long)W2, nullptr);
  conv_split<<<CCt / 1024, 256, 0, stream>>>(PART, UH, UL);

  // S = wq U^T -- split-K 4, private partial stores
  gemm_bt<true, 4, false><<<dim3(4, 4, B_ * 4), 256, 0, stream>>>(
      WQH, WQL, 0, UH, UL, (long long)W2, C_, 128, 4, C_, PART, nullptr,
      (long long)W2, nullptr);

  softmax_rows<<<(B_ * C_) / 4, 256, 0, stream>>>(PART, AQ, AK, bq, bk, bv, ATTN, OBIAS);

  // M = attn wv  (Bt = wv^T), bf16-hi store
  gemm_bt<false, 2, false><<<dim3(4, 4, B_), 256, 0, stream>>>(
      ATTN, nullptr, (long long)W2, WVT, nullptr, 0, C_, 512, 1, C_, nullptr,
      MH, (long long)W2, nullptr);
  // out = M x + obias  (Bt = xh^T)
  gemm_bt<false, 3, false><<<dim3(N_ / 128, 4, B_), 256, 0, stream>>>(
      MH, nullptr, (long long)W2, XHT, nullptr, (long long)((size_t)N_ * C_),
      C_, 512, 1, N_, out, nullptr, (long long)((size_t)C_ * N_), OBIAS);
}

// Round 4
// 276.523 us; speedup vs baseline: 1.2180x; 1.0076x over previous
//
#include <hip/hip_runtime.h>

// Channel self-attention, B=8 C=512 H=W=64 (N=4096), fp32 in/out.
//
//   G  = x x^T  (symmetric: upper-triangle tiles only)  split-bf16, split-K 8
//   U  = wk G                       split x split, split-K 4
//   S  = wq U^T + rank-1 bias terms split x split, split-K 4
//   attn = softmax_rows(S)
//   M  = attn wv                    single bf16
//   out = M x + (attn bv) 1^T       single bf16, Bt = xh^T
//
// gemm_bt: double-buffered counted-vmcnt pipeline, LDS XOR chunk swizzle
// (conflict-free, verified 0 SQ_LDS_BANK_CONFLICT), XCD slab swizzle for G.
// Split-K writes PRIVATE fp32 partial tiles (streaming stores); consumers
// reduce them. sx row-sums go to 8 XCD-local partial copies (slot = nt&7 =
// dispatching XCD) -- drops atomic contention 64x -> 8x per address; bias_vec
// sums the 8 slots on load.

typedef unsigned short u16;
typedef short v8s __attribute__((ext_vector_type(8)));
typedef float v4f __attribute__((ext_vector_type(4)));

#define B_ 8
#define C_ 512
#define N_ 4096

__device__ __forceinline__ u16 f2bf(float f) {
  unsigned int u = __builtin_bit_cast(unsigned int, f);
  u = u + 0x7fffu + ((u >> 16) & 1u);
  return (u16)(u >> 16);
}
__device__ __forceinline__ float bf2f(u16 h) {
  unsigned int u = ((unsigned int)h) << 16;
  return __builtin_bit_cast(float, u);
}
__device__ __forceinline__ void gld_lds16(const u16* g, u16* l) {
  __builtin_amdgcn_global_load_lds((__attribute__((address_space(1))) void*)(g),
                                   (__attribute__((address_space(3))) void*)(l),
                                   16, 0, 0);
}

// ---------------- BT-GEMM workhorse (dbuf pipelined + split-K) ----------------
// D[m][n] = sum_k A[m][k] * Bt[n][k].
// blockIdx.z = b * nsplit + ks; block covers K range [ks*Kc, ks*Kc+Kc).
// TRI: 10 upper-triangle (y<=x) 128-tiles of 512x512 C, XCD slab-swizzled.
// SPLIT: A,B each have hi/lo bf16 halves; 3 MFMA products (hh, hl, lh).
// EPI: 2 = bf16-hi store, 3 = fp32 + rowbias store,
//      4 = private fp32 partial-tile store to Cf (slot = z*ntiles + tile).
template <bool SPLIT, int EPI, bool TRI>
__global__ __launch_bounds__(256) void gemm_bt(
    const u16* __restrict__ Ah, const u16* __restrict__ Al, long long sA_,
    const u16* __restrict__ Bh, const u16* __restrict__ Bl, long long sB_,
    int K, int Kc, int nsplit, int ldc,
    float* __restrict__ Cf, u16* __restrict__ Ch,
    long long sC_, const float* __restrict__ rowbias) {
  constexpr int NB = SPLIT ? 4 : 2;  // buffers per stage: A0,A1,B0,B1 or A0,B0
  // [dbuf][which][128*32] : split = 64 KB (2 blocks/CU), nonsplit = 32 KB
  __shared__ __attribute__((aligned(16))) u16 pool[2 * NB * 128 * 32];

  int b, ks, ty_, tx_, tidx;
  if (TRI) {
    // bijective XCD slab swizzle: 640 blocks = 8 XCDs x 80; XCD i gets the
    // contiguous logical range [i*80, i*80+80) = one batch's 10 tiles x 8 ks.
    int L = (int)blockIdx.z * 10 + (int)blockIdx.x;
    int cpx = (B_ * nsplit * 10) >> 3;  // 80 for nsplit=8
    int Ls = (L & 7) * cpx + (L >> 3);
    int t = Ls % 10, z = Ls / 10;
    b = z / nsplit;
    ks = z % nsplit;
    tidx = t;
    ty_ = (t < 4) ? 0 : (t < 7) ? 1 : (t < 9) ? 2 : 3;
    tx_ = t - ((ty_ == 0) ? 0 : (ty_ == 1) ? 3 : (ty_ == 2) ? 5 : 6);
  } else {
    b = blockIdx.z / nsplit;
    ks = blockIdx.z % nsplit;
    ty_ = blockIdx.y;
    tx_ = blockIdx.x;
    tidx = ty_ * 4 + tx_;
  }
  int tid = threadIdx.x, lane = tid & 63, w = tid >> 6;
  const u16* pAh = Ah + (size_t)b * sA_ + (size_t)ty_ * 128 * K;
  const u16* pBh = Bh + (size_t)b * sB_ + (size_t)tx_ * 128 * K;
  const u16* pAl = SPLIT ? (Al + (size_t)b * sA_ + (size_t)ty_ * 128 * K) : pAh;
  const u16* pBl = SPLIT ? (Bl + (size_t)b * sB_ + (size_t)tx_ * 128 * K) : pBh;
  int wr = (w >> 1) * 64, wc = (w & 1) * 64;
  v4f acc[4][4] = {};

  // staging: 4 lanes per 64B row; source chunk XOR-pre-swizzled so that the
  // (linear-dest) global_load_lds lands LDS[row][s] = global[row][s ^ swz(row)]
  // with swz(row) = (row>>1)&3. Read side picks slot q ^ ((r>>1)&3) -> the
  // 64 lanes of a fragment read hit 64 distinct 16B slots: conflict-free.
  int srow_off = lane >> 2;
  int gcol = ((lane & 3) ^ ((lane >> 3) & 3)) * 8;

  const u16* sbase;
  int bufsel;
  if (SPLIT) {
    sbase = (w == 0) ? pAh : (w == 1) ? pAl : (w == 2) ? pBh : pBl;
    bufsel = w;
  } else {
    sbase = (w < 2) ? pAh : pBh;
    bufsel = (w >> 1);
  }

  int kbeg = ks * Kc;
  int nIter = Kc >> 5;

  auto STAGE = [&](int pb, int k0) {
    u16* lds = pool + (pb * NB + bufsel) * (128 * 32);
    if constexpr (SPLIT) {
      for (int t = 0; t < 8; ++t)
        gld_lds16(sbase + (size_t)(t * 16 + srow_off) * K + k0 + gcol,
                  lds + t * 16 * 32);
    } else {
      int o = (w & 1) * 4;
      for (int t = 0; t < 4; ++t) {
        int s = o + t;
        gld_lds16(sbase + (size_t)(s * 16 + srow_off) * K + k0 + gcol,
                  lds + s * 16 * 32);
      }
    }
  };

  int r = lane & 15, q = lane >> 4;
  int sw = (q ^ ((r >> 1) & 3)) * 8;  // swizzled read slot (shorts)

  STAGE(0, kbeg);
  for (int it = 0; it < nIter; ++it) {
    int cur = it & 1;
    bool pf = (it + 1 < nIter);
    if (pf) {
      STAGE(cur ^ 1, kbeg + (it + 1) * 32);
      // counted wait: just-issued 8 (or 4) may stay in flight; drains the
      // previous step's loads (the buffer we're about to read).
      if constexpr (SPLIT)
        asm volatile("s_waitcnt vmcnt(8)" ::: "memory");
      else
        asm volatile("s_waitcnt vmcnt(4)" ::: "memory");
    } else {
      asm volatile("s_waitcnt vmcnt(0)" ::: "memory");
    }
    __builtin_amdgcn_s_barrier();
    __builtin_amdgcn_sched_barrier(0);

    const u16* base = pool + cur * NB * (128 * 32);
    const u16* A0s = base;
    const u16* A1s = base + 128 * 32;
    const u16* B0s = base + (SPLIT ? 2 : 1) * (128 * 32);
    const u16* B1s = base + 3 * (128 * 32);
    v8s a0[4], a1[4], b0[4], b1[4];
    for (int mt = 0; mt < 4; ++mt) {
      int off = (wr + mt * 16 + r) * 32 + sw;
      a0[mt] = *(const v8s*)(const void*)(A0s + off);
      if (SPLIT) a1[mt] = *(const v8s*)(const void*)(A1s + off);
    }
    for (int nt = 0; nt < 4; ++nt) {
      int off = (wc + nt * 16 + r) * 32 + sw;
      b0[nt] = *(const v8s*)(const void*)(B0s + off);
      if (SPLIT) b1[nt] = *(const v8s*)(const void*)(B1s + off);
    }
    for (int mt = 0; mt < 4; ++mt)
      for (int nt = 0; nt < 4; ++nt) {
        acc[mt][nt] = __builtin_amdgcn_mfma_f32_16x16x32_bf16(a0[mt], b0[nt], acc[mt][nt], 0, 0, 0);
        if (SPLIT) {
          acc[mt][nt] = __builtin_amdgcn_mfma_f32_16x16x32_bf16(a0[mt], b1[nt], acc[mt][nt], 0, 0, 0);
          acc[mt][nt] = __builtin_amdgcn_mfma_f32_16x16x32_bf16(a1[mt], b0[nt], acc[mt][nt], 0, 0, 0);
        }
      }
    // WAR fence: all waves must finish reading buf 'cur' before the next
    // iteration's STAGE overwrites it.
    asm volatile("" ::: "memory");
    __builtin_amdgcn_s_barrier();
    asm volatile("" ::: "memory");
  }

  if (EPI == 4) {
    // private partial tile: slot = (b*nsplit+ks)*ntiles + tidx, [128][128] f32
    constexpr int NT = TRI ? 10 : 16;
    float* dstp = Cf + ((size_t)(b * nsplit + ks) * NT + tidx) * 16384;
    for (int mt = 0; mt < 4; ++mt)
      for (int nt = 0; nt < 4; ++nt) {
        int rl = wr + mt * 16 + q * 4;
        int cl = wc + nt * 16 + r;
        for (int e = 0; e < 4; ++e)
          dstp[(size_t)(rl + e) * 128 + cl] = acc[mt][nt][e];
      }
  } else {
    for (int mt = 0; mt < 4; ++mt)
      for (int nt = 0; nt < 4; ++nt) {
        int row0 = ty_ * 128 + wr + mt * 16 + q * 4;
        int col = tx_ * 128 + wc + nt * 16 + r;
        for (int e = 0; e < 4; ++e) {
          float vv = acc[mt][nt][e];
          size_t off = (size_t)b * sC_ + (size_t)(row0 + e) * ldc + col;
          if (EPI == 2) {
            Ch[off] = f2bf(vv);
          } else {
            Cf[off] = vv + rowbias[(size_t)b * C_ + row0 + e];
          }
        }
      }
  }
}

// G partial reduce: 160 blocks = (b:8) x (tri tile t:10) x (row half:2).
// b = blockIdx.x & 7 so consecutive blocks -> consecutive XCDs (partials for
// batch b were produced on XCD b). Pass 1: reduce 8 ks slots with coalesced
// float4 row-major reads, write hi/lo at (rq,cq), stage into padded LDS.
// Pass 2 (off-diag only): LDS-transposed read (stride 133: 16-bank, 2-way =
// free), coalesced ushort4 write of the mirrored (cq,rq) tile.
__global__ __launch_bounds__(256) void conv_split_g(
    const float* __restrict__ P, u16* __restrict__ h, u16* __restrict__ l) {
  __shared__ u16 th[64 * 133];
  __shared__ u16 tl[64 * 133];
  int j = blockIdx.x;
  int b = j & 7;
  int rest = j >> 3;         // 0..19
  int t = rest >> 1;         // tri tile 0..9
  int half = rest & 1;       // which 64-row half
  int rq = (t < 4) ? 0 : (t < 7) ? 1 : (t < 9) ? 2 : 3;
  int cq = t - ((rq == 0) ? 0 : (rq == 1) ? 3 : (rq == 2) ? 5 : 6);
  const float* p0 = P + ((size_t)(b * 8) * 10 + t) * 16384 + (size_t)(half * 64) * 128;
  int tid = threadIdx.x;
  int lr = tid >> 5;         // 0..7
  int c4 = (tid & 31) * 4;   // 0..124
  for (int it = 0; it < 8; ++it) {
    int row = it * 8 + lr;   // 0..63 within half
    const float* pr = p0 + (size_t)row * 128 + c4;
    float v[4] = {0.f, 0.f, 0.f, 0.f};
    for (int ks = 0; ks < 8; ++ks) {
      float4 x = *(const float4*)(pr + (size_t)ks * 10 * 16384);
      v[0] += x.x; v[1] += x.y; v[2] += x.z; v[3] += x.w;
    }
    u16 h4[4], l4[4];
    for (int e = 0; e < 4; ++e) {
      h4[e] = f2bf(v[e]);
      l4[e] = f2bf(v[e] - bf2f(h4[e]));
    }
    int gr = rq * 128 + half * 64 + row, gc = cq * 128 + c4;
    size_t go = ((size_t)b << 18) + (size_t)gr * C_ + gc;
    *(ushort4*)(h + go) = make_ushort4(h4[0], h4[1], h4[2], h4[3]);
    *(ushort4*)(l + go) = make_ushort4(l4[0], l4[1], l4[2], l4[3]);
    for (int e = 0; e < 4; ++e) {
      th[row * 133 + c4 + e] = h4[e];
      tl[row * 133 + c4 + e] = l4[e];
    }
  }
  if (rq == cq) return;  // diagonal: no mirror needed
  __syncthreads();
  int orw = tid >> 4;        // output-row step base (0..15)
  int oc4 = (tid & 15) * 4;  // 0..60 (original-row index within half)
  for (int it = 0; it < 8; ++it) {
    int orr = it * 16 + orw;  // 0..127 = original col
    u16 h4[4], l4[4];
    for (int e = 0; e < 4; ++e) {
      h4[e] = th[(oc4 + e) * 133 + orr];
      l4[e] = tl[(oc4 + e) * 133 + orr];
    }
    int gr = cq * 128 + orr, gc = rq * 128 + half * 64 + oc4;
    size_t go = ((size_t)b << 18) + (size_t)gr * C_ + gc;
    *(ushort4*)(h + go) = make_ushort4(h4[0], h4[1], h4[2], h4[3]);
    *(ushort4*)(l + go) = make_ushort4(l4[0], l4[1], l4[2], l4[3]);
  }
}

// U partial reduce (4 slots) -> hi/lo bf16 split buffers. float4 per thread.
__global__ __launch_bounds__(256) void conv_split(
    const float* __restrict__ P, u16* __restrict__ h, u16* __restrict__ l) {
  size_t i = ((size_t)blockIdx.x * 256 + threadIdx.x) * 4;
  int b = (int)(i >> 18);
  int r = (int)(i >> 9) & 511;
  int c = (int)i & 511;
  int t = (r >> 7) * 4 + (c >> 7);
  const float* p = P + ((size_t)(b * 4) * 16 + t) * 16384 +
                   (size_t)(r & 127) * 128 + (c & 127);
  float v[4] = {0.f, 0.f, 0.f, 0.f};
  for (int ks = 0; ks < 4; ++ks) {
    float4 x0 = *(const float4*)(p + (size_t)ks * 16 * 16384);
    v[0] += x0.x; v[1] += x0.y; v[2] += x0.z; v[3] += x0.w;
  }
  for (int j = 0; j < 4; ++j) {
    u16 hh = f2bf(v[j]);
    h[i + j] = hh;
    l[i + j] = f2bf(v[j] - bf2f(hh));
  }
}

// x (B,C,N) fp32 -> xh/xl bf16 split (same layout), xhT (B,N,C) bf16, sx row
// sums into 8 XCD-local partial copies (slot = nt&7 = dispatching XCD; only 8
// blocks contend per address, and each slot's lines stay XCD-local).
// Loads hoisted 4-deep ahead of the convert/store chain.
__global__ __launch_bounds__(256) void split_transpose(
    const float* __restrict__ x, u16* __restrict__ xh, u16* __restrict__ xl,
    u16* __restrict__ xhT, float* __restrict__ sx8) {
  __shared__ u16 tile[64 * 66];  // [n][c] stride 66
  int b = blockIdx.z, ct = blockIdx.y, nt = blockIdx.x;
  int tid = threadIdx.x;
  const float* xb = x + ((size_t)b * C_ + (size_t)ct * 64) * N_ + (size_t)nt * 64;
  float* sxs = sx8 + (size_t)(nt & 7) * (B_ * C_) + b * C_ + ct * 64;
  float4 v4[4];
  for (int it = 0; it < 4; ++it) {
    int idx = it * 1024 + tid * 4;
    v4[it] = *(const float4*)(xb + (size_t)(idx >> 6) * N_ + (idx & 63));
  }
  for (int it = 0; it < 4; ++it) {
    int idx = it * 1024 + tid * 4;
    int cl = idx >> 6;       // 0..63 local channel
    int nl = idx & 63;       // local n, multiple of 4
    float vv[4] = {v4[it].x, v4[it].y, v4[it].z, v4[it].w};
    u16 h4[4], l4[4];
    for (int j = 0; j < 4; ++j) {
      h4[j] = f2bf(vv[j]);
      l4[j] = f2bf(vv[j] - bf2f(h4[j]));
    }
    size_t go = ((size_t)b * C_ + ct * 64 + cl) * N_ + (size_t)nt * 64 + nl;
    *(ushort4*)(xh + go) = make_ushort4(h4[0], h4[1], h4[2], h4[3]);
    *(ushort4*)(xl + go) = make_ushort4(l4[0], l4[1], l4[2], l4[3]);
    for (int j = 0; j < 4; ++j) tile[(nl + j) * 66 + cl] = h4[j];
    float s = vv[0] + vv[1] + vv[2] + vv[3];
    s += __shfl_xor(s, 1); s += __shfl_xor(s, 2);
    s += __shfl_xor(s, 4); s += __shfl_xor(s, 8);
    if ((tid & 15) == 0) atomicAdd(&sxs[cl], s);
  }
  __syncthreads();
  for (int it = 0; it < 4; ++it) {
    int idx = it * 1024 + tid * 4;
    int nr = idx >> 6;       // local n row
    int c4 = idx & 63;       // local c, multiple of 4
    const u16* tp = tile + nr * 66 + c4;
    unsigned int lo = *(const unsigned int*)(const void*)(tp);
    unsigned int hi = *(const unsigned int*)(const void*)(tp + 2);
    size_t to = ((size_t)b * N_ + (size_t)nt * 64 + nr) * C_ + ct * 64 + c4;
    *(ushort4*)(xhT + to) = make_ushort4((u16)lo, (u16)(lo >> 16), (u16)hi, (u16)(hi >> 16));
  }
}

// wq,wk -> bf16 hi/lo splits; wv -> wvT bf16 (transposed).
// Blocks 0..127 zero the 8 sx partial copies (8 * B*C = 32768 floats).
__global__ __launch_bounds__(256) void prep_weights(
    const float* __restrict__ wq, const float* __restrict__ wk, const float* __restrict__ wv,
    u16* __restrict__ wqh, u16* __restrict__ wql, u16* __restrict__ wkh,
    u16* __restrict__ wkl, u16* __restrict__ wvT, float* __restrict__ sx8) {
  int idx = blockIdx.x * 256 + threadIdx.x;
  if (blockIdx.x < 128) sx8[idx] = 0.0f;
  float q = wq[idx];
  u16 qh = f2bf(q);
  wqh[idx] = qh;
  wql[idx] = f2bf(q - bf2f(qh));
  float k = wk[idx];
  u16 kh = f2bf(k);
  wkh[idx] = kh;
  wkl[idx] = f2bf(k - bf2f(kh));
  float v = wv[idx];
  wvT[(size_t)(idx & 511) * C_ + (idx >> 9)] = f2bf(v);
}

// aq[b,i] = sum_c wq[i,c] sx[b,c];  ak[b,j] = sum_c wk[j,c] sx[b,c]
// sx[b,c] = sum over the 8 partial slots (L2-resident, 64 extra loads/wave).
__global__ __launch_bounds__(256) void bias_vec(
    const float* __restrict__ wq, const float* __restrict__ wk,
    const float* __restrict__ sx8, float* __restrict__ aq, float* __restrict__ ak) {
  int gw = blockIdx.x * 4 + (threadIdx.x >> 6);  // 0..8191
  int lane = threadIdx.x & 63;
  int which = gw >> 12;
  int b = (gw >> 9) & 7, i = gw & 511;
  const float* wrow = (which ? wk : wq) + (size_t)i * C_;
  const float* sxb = sx8 + b * C_;
  float s = 0.f;
  for (int c = lane; c < C_; c += 64) {
    float sv = 0.f;
    for (int ss = 0; ss < 8; ++ss) sv += sxb[(size_t)ss * (B_ * C_) + c];
    s += wrow[c] * sv;
  }
  for (int o = 32; o; o >>= 1) s += __shfl_down(s, o);
  if (lane == 0) (which ? ak : aq)[b * C_ + i] = s;
}

// one wave per row: reduce 4 S-partials, add bias terms, softmax,
// emit attn bf16 + obias = attn.bv
__global__ __launch_bounds__(256) void softmax_rows(
    const float* __restrict__ P, const float* __restrict__ aq,
    const float* __restrict__ ak, const float* __restrict__ bq,
    const float* __restrict__ bk, const float* __restrict__ bv,
    u16* __restrict__ attn, float* __restrict__ obias) {
  int row = blockIdx.x * 4 + (threadIdx.x >> 6);  // b*512 + i
  int lane = threadIdx.x & 63;
  int b = row >> 9, i = row & 511;
  const float* akb = ak + b * C_;
  float aqi = aq[row], bqi = bq[i];
  float lv[8], ev[8];
  float m = -3.4e38f;
  for (int t = 0; t < 8; ++t) {
    int j = t * 64 + lane;
    int tile = (i >> 7) * 4 + (t >> 1);
    size_t base = ((size_t)(b * 4) * 16 + tile) * 16384 +
                  (size_t)(i & 127) * 128 + ((t & 1) * 64 + lane);
    float sv = 0.f;
    for (int ks = 0; ks < 4; ++ks) sv += P[base + (size_t)ks * 16 * 16384];
    float v = sv + aqi * bk[j] + bqi * (akb[j] + 4096.0f * bk[j]);
    lv[t] = v;
    m = fmaxf(m, v);
  }
  for (int o = 32; o; o >>= 1) m = fmaxf(m, __shfl_xor(m, o));
  float se = 0.f, sb = 0.f;
  for (int t = 0; t < 8; ++t) {
    int j = t * 64 + lane;
    float e = expf(lv[t] - m);
    ev[t] = e;
    se += e;
    sb += e * bv[j];
  }
  for (int o = 32; o; o >>= 1) {
    se += __shfl_xor(se, o);
    sb += __shfl_xor(sb, o);
  }
  float inv = 1.0f / se;
  for (int t = 0; t < 8; ++t) attn[(size_t)row * C_ + t * 64 + lane] = f2bf(ev[t] * inv);
  if (lane == 0) obias[row] = sb * inv;
}

extern "C" void kernel_launch(void* const* d_in, const int* in_sizes, int n_in,
                              void* d_out, int out_size, void* d_ws, size_t ws_size,
                              hipStream_t stream) {
  const float* x = (const float*)d_in[0];
  const float* wq = (const float*)d_in[1];
  const float* bq = (const float*)d_in[2];
  const float* wk = (const float*)d_in[3];
  const float* bk = (const float*)d_in[4];
  const float* wv = (const float*)d_in[5];
  const float* bv = (const float*)d_in[6];
  float* out = (float*)d_out;

  const size_t XN = (size_t)B_ * C_ * N_;   // 16.78M elems
  const size_t CCt = (size_t)B_ * C_ * C_;  // 2.10M elems
  const size_t W2 = (size_t)C_ * C_;
  const size_t PARTN = (size_t)B_ * 8 * 10 * 16384;  // 10.49M floats (41.9 MB)

  u16* XH = (u16*)d_ws;
  u16* XL = XH + XN;
  u16* XHT = XL + XN;
  float* PART = (float*)(XHT + XN);         // split-K partials (G:80, U/S:64 slots/b)
  u16* GH = (u16*)(PART + PARTN);
  u16* GL = GH + CCt;
  u16* UH = GL + CCt;
  u16* UL = UH + CCt;
  u16* ATTN = UL + CCt;
  u16* MH = ATTN + CCt;
  u16* WQH = MH + CCt;
  u16* WQL = WQH + W2;
  u16* WKH = WQL + W2;
  u16* WKL = WKH + W2;
  u16* WVT = WKL + W2;
  float* SX8 = (float*)(WVT + W2);          // 8 XCD-local sx partial copies
  float* AQ = SX8 + 8 * B_ * C_;
  float* AK = AQ + B_ * C_;
  float* OBIAS = AK + B_ * C_;

  prep_weights<<<W2 / 256, 256, 0, stream>>>(wq, wk, wv, WQH, WQL, WKH, WKL, WVT, SX8);
  split_transpose<<<dim3(N_ / 64, C_ / 64, B_), 256, 0, stream>>>(x, XH, XL, XHT, SX8);
  bias_vec<<<2048, 256, 0, stream>>>(wq, wk, SX8, AQ, AK);

  // G = x x^T  -- upper-triangle tiles, split-K 8, private partial stores
  gemm_bt<true, 4, true><<<dim3(10, 1, B_ * 8), 256, 0, stream>>>(
      XH, XL, (long long)((size_t)C_ * N_), XH, XL, (long long)((size_t)C_ * N_),
      N_, 512, 8, C_, PART, nullptr, (long long)W2, nullptr);
  conv_split_g<<<160, 256, 0, stream>>>(PART, GH, GL);

  // U = wk G   -- split-K 4 (A = wk split, Bt = G split; G symmetric)
  gemm_bt<true, 4, false><<<dim3(4, 4, B_ * 4), 256, 0, stream>>>(
      WKH, WKL, 0, GH, GL, (long long)W2, C_, 128, 4, C_, PART, nullptr,
      (long long)W2, nullptr);
  conv_split<<<CCt / 1024, 256, 0, stream>>>(PART, UH, UL);

  // S = wq U^T -- split-K 4, private partial stores
  gemm_bt<true, 4, false><<<dim3(4, 4, B_ * 4), 256, 0, stream>>>(
      WQH, WQL, 0, UH, UL, (long long)W2, C_, 128, 4, C_, PART, nullptr,
      (long long)W2, nullptr);

  softmax_rows<<<(B_ * C_) / 4, 256, 0, stream>>>(PART, AQ, AK, bq, bk, bv, ATTN, OBIAS);

  // M = attn wv  (Bt = wv^T), bf16-hi store
  gemm_bt<false, 2, false><<<dim3(4, 4, B_), 256, 0, stream>>>(
      ATTN, nullptr, (long long)W2, WVT, nullptr, 0, C_, 512, 1, C_, nullptr,
      MH, (long long)W2, nullptr);
  // out = M x + obias  (Bt = xh^T)
  gemm_bt<false, 3, false><<<dim3(N_ / 128, 4, B_), 256, 0, stream>>>(
      MH, nullptr, (long long)W2, XHT, nullptr, (long long)((size_t)N_ * C_),
      C_, 512, 1, N_, out, nullptr, (long long)((size_t)C_ * N_), OBIAS);
}